// Round 4
// baseline (218.679 us; speedup 1.0000x reference)
//
#include <hip/hip_runtime.h>

// ROIAlign (FPN multi-level, crop_and_resize style) for MI355X.
// Shapes (fixed): B=2, N=512, C=256, OUT=7, IMG=1024,
// strides {4,8,16,32} -> fm H=W {256,128,64,32}.
//
// R9 structure: block = 128 threads = 2 waves; each WAVE handles TWO cells
// with all 8 corner loads issued up-front (no loop-carried dep).
// Rationale: R8 proved occupancy (28 vs 32 waves/CU) is neutral; R6/R7's
// coarse waves lost to the 72-VGPR cap (serialized loads). The untested
// lever is per-wave MLP: R5/R8 waves stall on 4 outstanding loads per
// cold-L3 latency window. Here: 8 loads in flight per wave, 8 float4 =
// 32 data VGPRs (+~40 addr/coord) fits an 85-reg cap (launch_bounds 128,6
// -> 24 waves/CU; occupancy range 24-32 measured insensitive).
//  - block covers cells [4p, 4p+4) of one ROI; 13 blocks/ROI.
//  - XCD swizzle kept: all 13 blocks of a ROI -> same XCD slot -> the
//    ROI's pixel set fills ONE per-XCD L2.
//  - cells >= 49 masked on store only (addresses clamped -> loads safe);
//    no barriers anywhere.

#define B_SZ   2
#define N_ROI  512
#define CCH    256
#define OUT_S  7
#define NCELL  (OUT_S * OUT_S)
#define QUADS  13                      // ceil(49 / 4) cells per block

typedef float nfloat4 __attribute__((ext_vector_type(4)));

__global__ __launch_bounds__(128, 6)
void roialign_kernel(const float* __restrict__ fm2,
                     const float* __restrict__ fm3,
                     const float* __restrict__ fm4,
                     const float* __restrict__ fm5,
                     const float* __restrict__ rois,
                     float* __restrict__ out)
{
    // decode swizzled block id -> (roi, cell quad); wave id -> cell pair
    const int bidx = blockIdx.x;
    const int g    = bidx & 7;            // XCD slot == roi & 7
    const int q    = bidx >> 3;           // 0 .. 1663
    const int rhi  = q / QUADS;           // 0 .. 127  (roi >> 3)
    const int p    = q - rhi * QUADS;     // quad 0..12
    const int bn   = (rhi << 3) | g;      // ROI id 0..1023
    const int w_id = threadIdx.x >> 6;    // wave 0/1
    const int cA   = 4 * p + 2 * w_id;    // first cell of this wave
    if (cA >= NCELL) return;              // fully-pad wave (no barriers)
    const int cB   = cA + 1;              // second cell (maybe == 49 pad)
    const int vB   = (cB < NCELL);
    const int cBc  = vB ? cB : (NCELL - 1);   // clamped for safe addressing
    const int b    = bn >> 9;             // batch (N=512)

    // ---- per-ROI setup (wave-uniform) ----
    const float4 roi = ((const float4*)rois)[bn];   // x1,y1,x2,y2
    const float x1 = roi.x, y1 = roi.y;
    const float w  = roi.z - roi.x;
    const float h  = roi.w - roi.y;

    float lvf = log2f(sqrtf(w * h) * (1.0f / 224.0f)) + 4.0f;
    int lv = (int)rintf(lvf);                   // RNE, matches jnp.round
    lv = min(max(lv, 2), 5) - 2;                // 0..3

    const float* fm = (lv == 0) ? fm2 : (lv == 1) ? fm3 : (lv == 2) ? fm4 : fm5;
    const int    H      = 256 >> lv;            // H == W
    const float  stride = (float)(4 << lv);
    const float  scale  = (float)(H - 1) / (stride * (float)H);
    const float  Hm1f   = (float)(H - 1);

    const int c = (threadIdx.x & 63) * 4;       // 4 channels per lane
    const float*  base = fm + (size_t)b * (size_t)H * (size_t)H * CCH + c;
    const size_t  rowStride = (size_t)H * CCH;

    // ---- coordinates for BOTH cells (pure VALU, no loads yet) ----
    const int jyA = cA / OUT_S,  ixA = cA - jyA * OUT_S;
    const int jyB = cBc / OUT_S, ixB = cBc - jyB * OUT_S;

    const float cyA = (y1 + (float)jyA * (1.0f / 6.0f) * h) * scale;
    const float cxA = (x1 + (float)ixA * (1.0f / 6.0f) * w) * scale;
    const float cyB = (y1 + (float)jyB * (1.0f / 6.0f) * h) * scale;
    const float cxB = (x1 + (float)ixB * (1.0f / 6.0f) * w) * scale;

    const int vldA = (cyA >= 0.0f) & (cyA <= Hm1f) & (cxA >= 0.0f) & (cxA <= Hm1f);
    const int vldB = (cyB >= 0.0f) & (cyB <= Hm1f) & (cxB >= 0.0f) & (cxB <= Hm1f);

    const float cycA = fminf(fmaxf(cyA, 0.0f), Hm1f);
    const float cxcA = fminf(fmaxf(cxA, 0.0f), Hm1f);
    const float cycB = fminf(fmaxf(cyB, 0.0f), Hm1f);
    const float cxcB = fminf(fmaxf(cxB, 0.0f), Hm1f);

    const int   y0A = (int)floorf(cycA), x0A = (int)floorf(cxcA);
    const int   y0B = (int)floorf(cycB), x0B = (int)floorf(cxcB);
    const float ylA = cycA - (float)y0A, xlA = cxcA - (float)x0A;
    const float ylB = cycB - (float)y0B, xlB = cxcB - (float)x0B;
    const int   y1A = min(y0A + 1, H - 1), x1A = min(x0A + 1, H - 1);
    const int   y1B = min(y0B + 1, H - 1), x1B = min(x0B + 1, H - 1);

    const float* rowTA = base + (size_t)y0A * rowStride;
    const float* rowBA = base + (size_t)y1A * rowStride;
    const float* rowTB = base + (size_t)y0B * rowStride;
    const float* rowBB = base + (size_t)y1B * rowStride;

    // ---- ALL EIGHT loads issued back-to-back (8 in flight per wave) ----
    const float4 tlA = *(const float4*)(rowTA + x0A * CCH);
    const float4 trA = *(const float4*)(rowTA + x1A * CCH);
    const float4 blA = *(const float4*)(rowBA + x0A * CCH);
    const float4 brA = *(const float4*)(rowBA + x1A * CCH);
    const float4 tlB = *(const float4*)(rowTB + x0B * CCH);
    const float4 trB = *(const float4*)(rowTB + x1B * CCH);
    const float4 blB = *(const float4*)(rowBB + x0B * CCH);
    const float4 brB = *(const float4*)(rowBB + x1B * CCH);

    float* outbase = out + (size_t)bn * NCELL * CCH + c;

    // ---- cell A: lerp + NT store ----
    {
        nfloat4 o;
        {
            const float t  = tlA.x + (trA.x - tlA.x) * xlA;
            const float bo = blA.x + (brA.x - blA.x) * xlA;
            o.x = t + (bo - t) * ylA;
        }
        {
            const float t  = tlA.y + (trA.y - tlA.y) * xlA;
            const float bo = blA.y + (brA.y - blA.y) * xlA;
            o.y = t + (bo - t) * ylA;
        }
        {
            const float t  = tlA.z + (trA.z - tlA.z) * xlA;
            const float bo = blA.z + (brA.z - blA.z) * xlA;
            o.z = t + (bo - t) * ylA;
        }
        {
            const float t  = tlA.w + (trA.w - tlA.w) * xlA;
            const float bo = blA.w + (brA.w - blA.w) * xlA;
            o.w = t + (bo - t) * ylA;
        }
        if (!vldA) { o.x = 0.0f; o.y = 0.0f; o.z = 0.0f; o.w = 0.0f; }
        __builtin_nontemporal_store(
            o, (nfloat4*)(outbase + (size_t)cA * CCH));
    }

    // ---- cell B: lerp + NT store (masked if pad) ----
    if (vB) {
        nfloat4 o;
        {
            const float t  = tlB.x + (trB.x - tlB.x) * xlB;
            const float bo = blB.x + (brB.x - blB.x) * xlB;
            o.x = t + (bo - t) * ylB;
        }
        {
            const float t  = tlB.y + (trB.y - tlB.y) * xlB;
            const float bo = blB.y + (brB.y - blB.y) * xlB;
            o.y = t + (bo - t) * ylB;
        }
        {
            const float t  = tlB.z + (trB.z - tlB.z) * xlB;
            const float bo = blB.z + (brB.z - blB.z) * xlB;
            o.z = t + (bo - t) * ylB;
        }
        {
            const float t  = tlB.w + (trB.w - tlB.w) * xlB;
            const float bo = blB.w + (brB.w - blB.w) * xlB;
            o.w = t + (bo - t) * ylB;
        }
        if (!vldB) { o.x = 0.0f; o.y = 0.0f; o.z = 0.0f; o.w = 0.0f; }
        __builtin_nontemporal_store(
            o, (nfloat4*)(outbase + (size_t)cB * CCH));
    }
}

extern "C" void kernel_launch(void* const* d_in, const int* in_sizes, int n_in,
                              void* d_out, int out_size, void* d_ws, size_t ws_size,
                              hipStream_t stream) {
    const float* fm2  = (const float*)d_in[0];
    const float* fm3  = (const float*)d_in[1];
    const float* fm4  = (const float*)d_in[2];
    const float* fm5  = (const float*)d_in[3];
    const float* rois = (const float*)d_in[4];
    float* out = (float*)d_out;

    dim3 grid(8 * (N_ROI * B_SZ / 8) * QUADS);   // 13312 blocks (XCD-swizzled)
    dim3 block(128);                             // 2 waves; each wave = 2 cells
    hipLaunchKernelGGL(roialign_kernel, grid, block, 0, stream,
                       fm2, fm3, fm4, fm5, rois, out);
}